// Round 9
// baseline (852.059 us; speedup 1.0000x reference)
//
#include <hip/hip_runtime.h>
#include <hip/hip_bf16.h>

#define NN 60000
#define NE 600000
#define DD 128
#define NTOT (NE + NN)
#define NB ((NN + 255) / 256)   // 235 blocks for scan

typedef __attribute__((ext_vector_type(8))) short short8;
typedef __attribute__((ext_vector_type(4))) float f32x4;

__device__ __forceinline__ unsigned short f2bf(float f) {
    unsigned int u = __float_as_uint(f);
    unsigned int r = (u + 0x7FFF + ((u >> 16) & 1)) >> 16;  // RNE
    return (unsigned short)r;
}
__device__ __forceinline__ float bflo(unsigned int u) { return __uint_as_float(u << 16); }
__device__ __forceinline__ float bfhi(unsigned int u) { return __uint_as_float(u & 0xFFFF0000u); }

// ---- degree (edges only; +1 self-loop folded in later) ----
__global__ __launch_bounds__(256) void deg_kernel(const int* __restrict__ dst, int* __restrict__ deg) {
    int e = blockIdx.x * 256 + threadIdx.x;
    if (e < NE) atomicAdd(&deg[dst[e]], 1);
}

// ---- scanA: per-block sums of (deg+1), fused dinv ----
__global__ __launch_bounds__(256) void scanA_kernel(const int* __restrict__ deg, int* __restrict__ partials,
                                                    float* __restrict__ dinv) {
    __shared__ int lds[256];
    int i = blockIdx.x * 256 + threadIdx.x;
    int dv = (i < NN) ? deg[i] : 0;
    if (i < NN) dinv[i] = rsqrtf((float)(dv + 1));
    int v = (i < NN) ? dv + 1 : 0;
    lds[threadIdx.x] = v;
    __syncthreads();
    for (int off = 128; off > 0; off >>= 1) {
        if (threadIdx.x < off) lds[threadIdx.x] += lds[threadIdx.x + off];
        __syncthreads();
    }
    if (threadIdx.x == 0) partials[blockIdx.x] = lds[0];
}

__global__ __launch_bounds__(256) void scanB_kernel(const int* __restrict__ partials,
                                                    int* __restrict__ blockoff,
                                                    int* __restrict__ rowptr) {
    __shared__ int lds[256];
    int t = threadIdx.x;
    int v = (t < NB) ? partials[t] : 0;
    lds[t] = v;
    __syncthreads();
    for (int off = 1; off < 256; off <<= 1) {
        int u = (t >= off) ? lds[t - off] : 0;
        __syncthreads();
        lds[t] += u;
        __syncthreads();
    }
    if (t < NB) blockoff[t] = lds[t] - v;  // exclusive
    if (t == 0) rowptr[NN] = NTOT;
}

__global__ __launch_bounds__(256) void scanC_kernel(const int* __restrict__ deg,
                                                    const int* __restrict__ blockoff,
                                                    int* __restrict__ rowptr) {
    __shared__ int lds[256];
    int i = blockIdx.x * 256 + threadIdx.x;
    int t = threadIdx.x;
    int v = (i < NN) ? deg[i] + 1 : 0;
    lds[t] = v;
    __syncthreads();
    for (int off = 1; off < 256; off <<= 1) {
        int u = (t >= off) ? lds[t - off] : 0;
        __syncthreads();
        lds[t] += u;
        __syncthreads();
    }
    if (i < NN) rowptr[i] = blockoff[blockIdx.x] + lds[t] - v;
}

// ---- CSR fill: packed int2{src, coef_bits} -> ONE 8B scattered store per edge ----
__global__ __launch_bounds__(256) void fill_kernel(const int* __restrict__ src, const int* __restrict__ dst,
                                                   const int* __restrict__ rowptr, int* __restrict__ cursor,
                                                   const float* __restrict__ dinv,
                                                   int2* __restrict__ csr) {
    int e = blockIdx.x * 256 + threadIdx.x;
    if (e >= NTOT) return;
    int s, t;
    if (e < NE) { s = src[e]; t = dst[e]; }
    else { s = t = e - NE; }
    int pos = atomicAdd(&cursor[t], 1);
    int2 rec;
    rec.x = s;
    rec.y = __float_as_int(dinv[s] * dinv[t]);
    csr[rowptr[t] + pos] = rec;
}

// ---- W convert+transpose, all 3 layers: Wt[L][n][k] bf16 <- W_L[k][n] fp32 ----
__global__ __launch_bounds__(256) void wcvt_kernel(const float* __restrict__ W0, const float* __restrict__ W1,
                                                   const float* __restrict__ W2, unsigned short* __restrict__ Wt) {
    int idx = blockIdx.x * 256 + threadIdx.x;  // 3*64*128 items
    if (idx >= 3 * 64 * DD) return;
    int L = idx / (64 * DD);
    int r = idx - L * 64 * DD;
    const float* W = (L == 0) ? W0 : (L == 1) ? W1 : W2;
    int k2 = (r >> 7) * 2;
    int n = r & 127;
    unsigned int b0 = f2bf(W[k2 * DD + n]);
    unsigned int b1 = f2bf(W[(k2 + 1) * DD + n]);
    ((unsigned int*)Wt)[(L * DD * DD + n * DD + k2) >> 1] = b0 | (b1 << 16);
}

// ---- MFMA GEMM: C_bf16[NN x 128] = f(A) @ W ----
// BF16IN: A is bf16 (layers 1,2; normp applied); else fp32 (layer 0, normp null).
// One wave per 16 rows; 8 col-tiles of 16; K=128 in 4 chunks of 32.
// Layouts (m89/m120): A/B frag own=lane&15,k=(lane>>4)*8+j; C/D col=lane&15,row=(lane>>4)*4+reg.
// NOTE: no waves/EU hint — (256,4) caused 64-VGPR cap + acc spill (R3: 1 GiB traffic).
template <bool BF16IN>
__global__ __launch_bounds__(256) void gemm_mfma_kernel(const void* __restrict__ Ain,
                                                        const unsigned short* __restrict__ Wt,
                                                        const float* __restrict__ normp,
                                                        unsigned short* __restrict__ C) {
    __shared__ float lds[4][16][132];  // 33 KB, per-wave repack tiles
    int tid = threadIdx.x;
    int wslot = tid >> 6;
    int wrow0 = (blockIdx.x * 4 + wslot) * 16;
    if (wrow0 >= NN) return;
    int l = tid & 63;
    int m = l & 15;
    int q = l >> 4;

    f32x4 acc[8];
#pragma unroll
    for (int i = 0; i < 8; i++) acc[i] = (f32x4){0.f, 0.f, 0.f, 0.f};

#pragma unroll
    for (int kc = 0; kc < 4; kc++) {
        int k0 = kc * 32 + q * 8;
        float a[8];
        if (BF16IN) {
            const unsigned short* arow = (const unsigned short*)Ain + (size_t)(wrow0 + m) * DD;
            uint4 u = *(const uint4*)(arow + k0);
            a[0] = bflo(u.x); a[1] = bfhi(u.x); a[2] = bflo(u.y); a[3] = bfhi(u.y);
            a[4] = bflo(u.z); a[5] = bfhi(u.z); a[6] = bflo(u.w); a[7] = bfhi(u.w);
        } else {
            const float* arow = (const float*)Ain + (size_t)(wrow0 + m) * DD;
            float4 a0 = *(const float4*)(arow + k0);
            float4 a1 = *(const float4*)(arow + k0 + 4);
            a[0] = a0.x; a[1] = a0.y; a[2] = a0.z; a[3] = a0.w;
            a[4] = a1.x; a[5] = a1.y; a[6] = a1.z; a[7] = a1.w;
        }
        if (normp) {
#pragma unroll
            for (int j = 0; j < 8; j++) {
                float v = fmaf(a[j], normp[k0 + j], normp[128 + k0 + j]);
                a[j] = (v >= 0.f) ? v : 0.01f * v;
            }
        }
        short8 af;
#pragma unroll
        for (int j = 0; j < 8; j++) af[j] = (short)f2bf(a[j]);
#pragma unroll
        for (int nt = 0; nt < 8; nt++) {
            short8 bf = *(const short8*)(Wt + (size_t)(nt * 16 + m) * DD + k0);
            acc[nt] = __builtin_amdgcn_mfma_f32_16x16x32_bf16(af, bf, acc[nt], 0, 0, 0);
        }
    }

    // epilogue: repack through per-wave LDS tile (wave-internal, no barrier needed)
    float (*tile)[132] = lds[wslot];
#pragma unroll
    for (int nt = 0; nt < 8; nt++)
#pragma unroll
        for (int r = 0; r < 4; r++)
            tile[q * 4 + r][nt * 16 + m] = acc[nt][r];

    unsigned short* crow = C + (size_t)(wrow0 + m) * DD;
#pragma unroll
    for (int j = 0; j < 8; j++) {
        int col = q * 4 + 16 * j;
        float4 v = *(float4*)&tile[m][col];
        unsigned int lo = f2bf(v.x) | ((unsigned int)f2bf(v.y) << 16);
        unsigned int hi = f2bf(v.z) | ((unsigned int)f2bf(v.w) << 16);
        uint2 p; p.x = lo; p.y = hi;
        *(uint2*)(crow + col) = p;  // 8 B aligned
    }
}

// ---- CSR gather-aggregate + FUSED BN stats ----
// Block = 4 waves x 4 nodes/wave (grid 3750 -> 15000 waves: latency-bound gather
// needs TLP; R8's 16 nodes/wave at grid 938 collapsed occupancy 87->30%).
// Lane owns feature pair (2l, 2l+1); stats on rounded-bf16 stored values;
// component-major LDS reduce (conflict-free); 256 atomics/block.
__global__ __launch_bounds__(256) void gather_kernel(const unsigned short* __restrict__ xw,
                                                     const int* __restrict__ rowptr,
                                                     const int2* __restrict__ csr,
                                                     unsigned short* __restrict__ agg,
                                                     float* __restrict__ sums) {
    int w = threadIdx.x >> 6;
    int l = threadIdx.x & 63;
    int base = (blockIdx.x * 4 + w) * 4;   // NN = 60000 = 3750*16 exactly
    float s0 = 0.f, q0 = 0.f, s1 = 0.f, q1 = 0.f;
#pragma unroll
    for (int j = 0; j < 4; j++) {
        int wid = base + j;
        int beg = rowptr[wid], end = rowptr[wid + 1];
        float ax = 0.f, ay = 0.f;
        int i = beg;
        for (; i + 4 <= end; i += 4) {
            int2 r0 = csr[i], r1 = csr[i + 1], r2 = csr[i + 2], r3 = csr[i + 3];
            unsigned int u0 = *(const unsigned int*)(xw + (size_t)r0.x * DD + 2 * l);
            unsigned int u1 = *(const unsigned int*)(xw + (size_t)r1.x * DD + 2 * l);
            unsigned int u2 = *(const unsigned int*)(xw + (size_t)r2.x * DD + 2 * l);
            unsigned int u3 = *(const unsigned int*)(xw + (size_t)r3.x * DD + 2 * l);
            float c0 = __int_as_float(r0.y), c1 = __int_as_float(r1.y);
            float c2 = __int_as_float(r2.y), c3 = __int_as_float(r3.y);
            ax += bflo(u0) * c0 + bflo(u1) * c1 + bflo(u2) * c2 + bflo(u3) * c3;
            ay += bfhi(u0) * c0 + bfhi(u1) * c1 + bfhi(u2) * c2 + bfhi(u3) * c3;
        }
        for (; i < end; i++) {
            int2 r0 = csr[i];
            unsigned int u0 = *(const unsigned int*)(xw + (size_t)r0.x * DD + 2 * l);
            float c0 = __int_as_float(r0.y);
            ax += bflo(u0) * c0;
            ay += bfhi(u0) * c0;
        }
        unsigned int pa = (unsigned int)f2bf(ax) | ((unsigned int)f2bf(ay) << 16);
        ((unsigned int*)(agg + (size_t)wid * DD))[l] = pa;
        float rx = bflo(pa), ry = bfhi(pa);  // stats on stored (rounded) values
        s0 += rx; q0 += rx * rx;
        s1 += ry; q1 += ry * ry;
    }
    __shared__ float lds[4][4][64];  // [wave][component][lane] — conflict-free
    lds[w][0][l] = s0; lds[w][1][l] = q0;
    lds[w][2][l] = s1; lds[w][3][l] = q1;
    __syncthreads();
    // thread t: feature-pair l2 = t&63, component jj = t>>6
    int l2 = threadIdx.x & 63, jj = threadIdx.x >> 6;
    float v = lds[0][jj][l2] + lds[1][jj][l2] + lds[2][jj][l2] + lds[3][jj][l2];
    // jj=0: sum(2l2); jj=1: sumsq(2l2); jj=2: sum(2l2+1); jj=3: sumsq(2l2+1)
    int addr = (jj & 1) * 128 + 2 * l2 + (jj >> 1);
    atomicAdd(&sums[addr], v);
}

// ---- fold sums -> scale/shift: scale=g*rsqrt(var+eps), shift=be-mu*scale ----
__global__ __launch_bounds__(128) void bnfin_kernel(const float* __restrict__ sums,
                                                    const float* __restrict__ g,
                                                    const float* __restrict__ be,
                                                    float* __restrict__ normp) {
    int d = threadIdx.x;
    const float invN = 1.0f / (float)NN;
    float mu = sums[d] * invN;
    float var = sums[128 + d] * invN - mu * mu;
    float sc = rsqrtf(var + 1e-5f) * g[d];
    normp[d] = sc;
    normp[128 + d] = be[d] - mu * sc;
}

// ---- final: out_fp32 = bf16(agg)*scale+shift (normp precomputed by bnfin) ----
__global__ __launch_bounds__(256) void bnapply_kernel(const unsigned short* __restrict__ h,
                                                      const float* __restrict__ normp,
                                                      float* __restrict__ out) {
    int idx = blockIdx.x * 256 + threadIdx.x;  // one per 4 elements
    if (idx >= NN * DD / 4) return;
    int d = (idx * 4) & 127;
    uint2 u = *(const uint2*)(h + idx * 4);
    float4 sc = *(const float4*)&normp[d];
    float4 sh = *(const float4*)&normp[128 + d];
    float4 o;
    o.x = fmaf(bflo(u.x), sc.x, sh.x);
    o.y = fmaf(bfhi(u.x), sc.y, sh.y);
    o.z = fmaf(bflo(u.y), sc.z, sh.z);
    o.w = fmaf(bfhi(u.y), sc.w, sh.w);
    *(float4*)&out[idx * 4] = o;
}

extern "C" void kernel_launch(void* const* d_in, const int* in_sizes, int n_in,
                              void* d_out, int out_size, void* d_ws, size_t ws_size,
                              hipStream_t stream) {
    const float* x = (const float*)d_in[0];
    const int* ei = (const int*)d_in[1];
    const int* srcp = ei;
    const int* dstp = ei + NE;
    const float* w[3]  = {(const float*)d_in[2], (const float*)d_in[6],  (const float*)d_in[10]};
    const float* g[3]  = {(const float*)d_in[4], (const float*)d_in[8],  (const float*)d_in[12]};
    const float* be[3] = {(const float*)d_in[5], (const float*)d_in[9],  (const float*)d_in[13]};

    // workspace layout (~43 MB), all chunks 16-B aligned
    unsigned short* xwb  = (unsigned short*)d_ws;        // bf16 xw  [NN*DD]
    unsigned short* aggb = xwb + (size_t)NN * DD;        // bf16 agg [NN*DD]
    int* deg    = (int*)(aggb + (size_t)NN * DD);        // [NN]
    int* cursor = deg + NN;                              // [NN]
    int* rowptr = cursor + NN;                           // [NN+16]
    float* dinv = (float*)(rowptr + NN + 16);            // [NN]
    float* sums = dinv + NN;                             // [3*256]
    float* ss   = sums + 3 * 256;                        // [3*256] scale/shift per layer
    int* partials = (int*)(ss + 3 * 256);                // [256]
    int* blockoff = partials + 256;                      // [256]
    unsigned short* Wt = (unsigned short*)(blockoff + 256);  // [3*128*128] bf16
    int2* csr = (int2*)(Wt + 3 * DD * DD);               // [NTOT] packed {src, coef}
    float* out = (float*)d_out;

    // ---- CSR build (once; edge_index constant across layers) ----
    hipMemsetAsync(deg, 0, 2 * NN * sizeof(int), stream);        // deg + cursor
    hipMemsetAsync(sums, 0, 3 * 256 * sizeof(float), stream);    // all layers' stats
    deg_kernel<<<(NE + 255) / 256, 256, 0, stream>>>(dstp, deg);
    scanA_kernel<<<NB, 256, 0, stream>>>(deg, partials, dinv);
    scanB_kernel<<<1, 256, 0, stream>>>(partials, blockoff, rowptr);
    scanC_kernel<<<NB, 256, 0, stream>>>(deg, blockoff, rowptr);
    fill_kernel<<<(NTOT + 255) / 256, 256, 0, stream>>>(srcp, dstp, rowptr, cursor, dinv, csr);
    wcvt_kernel<<<(3 * 64 * DD + 255) / 256, 256, 0, stream>>>(w[0], w[1], w[2], Wt);

    const int GEMM_GRID = (NN / 16 + 3) / 4;    // 938
    const int GATHER_GRID = NN / 16;            // 3750 (4 waves x 4 nodes)
    for (int L = 0; L < 3; ++L) {
        const float* normp = (L == 0) ? nullptr : (ss + (L - 1) * 256);
        if (L == 0)
            gemm_mfma_kernel<false><<<GEMM_GRID, 256, 0, stream>>>(x, Wt, normp, xwb);
        else
            gemm_mfma_kernel<true><<<GEMM_GRID, 256, 0, stream>>>(aggb, Wt + L * DD * DD, normp, xwb);
        gather_kernel<<<GATHER_GRID, 256, 0, stream>>>(xwb, rowptr, csr, aggb, sums + L * 256);
        bnfin_kernel<<<1, 128, 0, stream>>>(sums + L * 256, g[L], be[L], ss + L * 256);
        if (L == 2)
            bnapply_kernel<<<(NN * DD / 4 + 255) / 256, 256, 0, stream>>>(aggb, ss + L * 256, out);
    }
}

// Round 10
// 430.414 us; speedup vs baseline: 1.9796x; 1.9796x over previous
//
#include <hip/hip_runtime.h>
#include <hip/hip_bf16.h>

#define NN 60000
#define NE 600000
#define DD 128
#define NTOT (NE + NN)
#define NB ((NN + 255) / 256)   // 235 blocks for scan

typedef __attribute__((ext_vector_type(8))) short short8;
typedef __attribute__((ext_vector_type(4))) float f32x4;

__device__ __forceinline__ unsigned short f2bf(float f) {
    unsigned int u = __float_as_uint(f);
    unsigned int r = (u + 0x7FFF + ((u >> 16) & 1)) >> 16;  // RNE
    return (unsigned short)r;
}
__device__ __forceinline__ float bflo(unsigned int u) { return __uint_as_float(u << 16); }
__device__ __forceinline__ float bfhi(unsigned int u) { return __uint_as_float(u & 0xFFFF0000u); }

// ---- degree (edges only; +1 self-loop folded in later) ----
__global__ __launch_bounds__(256) void deg_kernel(const int* __restrict__ dst, int* __restrict__ deg) {
    int e = blockIdx.x * 256 + threadIdx.x;
    if (e < NE) atomicAdd(&deg[dst[e]], 1);
}

// ---- scanA: per-block sums of (deg+1), fused dinv ----
__global__ __launch_bounds__(256) void scanA_kernel(const int* __restrict__ deg, int* __restrict__ partials,
                                                    float* __restrict__ dinv) {
    __shared__ int lds[256];
    int i = blockIdx.x * 256 + threadIdx.x;
    int dv = (i < NN) ? deg[i] : 0;
    if (i < NN) dinv[i] = rsqrtf((float)(dv + 1));
    int v = (i < NN) ? dv + 1 : 0;
    lds[threadIdx.x] = v;
    __syncthreads();
    for (int off = 128; off > 0; off >>= 1) {
        if (threadIdx.x < off) lds[threadIdx.x] += lds[threadIdx.x + off];
        __syncthreads();
    }
    if (threadIdx.x == 0) partials[blockIdx.x] = lds[0];
}

__global__ __launch_bounds__(256) void scanB_kernel(const int* __restrict__ partials,
                                                    int* __restrict__ blockoff,
                                                    int* __restrict__ rowptr) {
    __shared__ int lds[256];
    int t = threadIdx.x;
    int v = (t < NB) ? partials[t] : 0;
    lds[t] = v;
    __syncthreads();
    for (int off = 1; off < 256; off <<= 1) {
        int u = (t >= off) ? lds[t - off] : 0;
        __syncthreads();
        lds[t] += u;
        __syncthreads();
    }
    if (t < NB) blockoff[t] = lds[t] - v;  // exclusive
    if (t == 0) rowptr[NN] = NTOT;
}

__global__ __launch_bounds__(256) void scanC_kernel(const int* __restrict__ deg,
                                                    const int* __restrict__ blockoff,
                                                    int* __restrict__ rowptr) {
    __shared__ int lds[256];
    int i = blockIdx.x * 256 + threadIdx.x;
    int t = threadIdx.x;
    int v = (i < NN) ? deg[i] + 1 : 0;
    lds[t] = v;
    __syncthreads();
    for (int off = 1; off < 256; off <<= 1) {
        int u = (t >= off) ? lds[t - off] : 0;
        __syncthreads();
        lds[t] += u;
        __syncthreads();
    }
    if (i < NN) rowptr[i] = blockoff[blockIdx.x] + lds[t] - v;
}

// ---- CSR fill: packed int2{src, coef_bits} -> ONE 8B scattered store per edge ----
__global__ __launch_bounds__(256) void fill_kernel(const int* __restrict__ src, const int* __restrict__ dst,
                                                   const int* __restrict__ rowptr, int* __restrict__ cursor,
                                                   const float* __restrict__ dinv,
                                                   int2* __restrict__ csr) {
    int e = blockIdx.x * 256 + threadIdx.x;
    if (e >= NTOT) return;
    int s, t;
    if (e < NE) { s = src[e]; t = dst[e]; }
    else { s = t = e - NE; }
    int pos = atomicAdd(&cursor[t], 1);
    int2 rec;
    rec.x = s;
    rec.y = __float_as_int(dinv[s] * dinv[t]);
    csr[rowptr[t] + pos] = rec;
}

// ---- W convert+transpose, all 3 layers: Wt[L][n][k] bf16 <- W_L[k][n] fp32 ----
__global__ __launch_bounds__(256) void wcvt_kernel(const float* __restrict__ W0, const float* __restrict__ W1,
                                                   const float* __restrict__ W2, unsigned short* __restrict__ Wt) {
    int idx = blockIdx.x * 256 + threadIdx.x;  // 3*64*128 items
    if (idx >= 3 * 64 * DD) return;
    int L = idx / (64 * DD);
    int r = idx - L * 64 * DD;
    const float* W = (L == 0) ? W0 : (L == 1) ? W1 : W2;
    int k2 = (r >> 7) * 2;
    int n = r & 127;
    unsigned int b0 = f2bf(W[k2 * DD + n]);
    unsigned int b1 = f2bf(W[(k2 + 1) * DD + n]);
    ((unsigned int*)Wt)[(L * DD * DD + n * DD + k2) >> 1] = b0 | (b1 << 16);
}

// ---- MFMA GEMM: C_bf16[NN x 128] = f(A) @ W ----
// BF16IN: A is bf16 (layers 1,2; normp applied); else fp32 (layer 0, normp null).
// One wave per 16 rows; 8 col-tiles of 16; K=128 in 4 chunks of 32.
// Layouts (m89/m120): A/B frag own=lane&15,k=(lane>>4)*8+j; C/D col=lane&15,row=(lane>>4)*4+reg.
// NOTE: no waves/EU hint — (256,4) caused 64-VGPR cap + acc spill (R3: 1 GiB traffic).
template <bool BF16IN>
__global__ __launch_bounds__(256) void gemm_mfma_kernel(const void* __restrict__ Ain,
                                                        const unsigned short* __restrict__ Wt,
                                                        const float* __restrict__ normp,
                                                        unsigned short* __restrict__ C) {
    __shared__ float lds[4][16][132];  // 33 KB, per-wave repack tiles
    int tid = threadIdx.x;
    int wslot = tid >> 6;
    int wrow0 = (blockIdx.x * 4 + wslot) * 16;
    if (wrow0 >= NN) return;
    int l = tid & 63;
    int m = l & 15;
    int q = l >> 4;

    f32x4 acc[8];
#pragma unroll
    for (int i = 0; i < 8; i++) acc[i] = (f32x4){0.f, 0.f, 0.f, 0.f};

#pragma unroll
    for (int kc = 0; kc < 4; kc++) {
        int k0 = kc * 32 + q * 8;
        float a[8];
        if (BF16IN) {
            const unsigned short* arow = (const unsigned short*)Ain + (size_t)(wrow0 + m) * DD;
            uint4 u = *(const uint4*)(arow + k0);
            a[0] = bflo(u.x); a[1] = bfhi(u.x); a[2] = bflo(u.y); a[3] = bfhi(u.y);
            a[4] = bflo(u.z); a[5] = bfhi(u.z); a[6] = bflo(u.w); a[7] = bfhi(u.w);
        } else {
            const float* arow = (const float*)Ain + (size_t)(wrow0 + m) * DD;
            float4 a0 = *(const float4*)(arow + k0);
            float4 a1 = *(const float4*)(arow + k0 + 4);
            a[0] = a0.x; a[1] = a0.y; a[2] = a0.z; a[3] = a0.w;
            a[4] = a1.x; a[5] = a1.y; a[6] = a1.z; a[7] = a1.w;
        }
        if (normp) {
#pragma unroll
            for (int j = 0; j < 8; j++) {
                float v = fmaf(a[j], normp[k0 + j], normp[128 + k0 + j]);
                a[j] = (v >= 0.f) ? v : 0.01f * v;
            }
        }
        short8 af;
#pragma unroll
        for (int j = 0; j < 8; j++) af[j] = (short)f2bf(a[j]);
#pragma unroll
        for (int nt = 0; nt < 8; nt++) {
            short8 bf = *(const short8*)(Wt + (size_t)(nt * 16 + m) * DD + k0);
            acc[nt] = __builtin_amdgcn_mfma_f32_16x16x32_bf16(af, bf, acc[nt], 0, 0, 0);
        }
    }

    // epilogue: repack through per-wave LDS tile (wave-internal, no barrier needed)
    float (*tile)[132] = lds[wslot];
#pragma unroll
    for (int nt = 0; nt < 8; nt++)
#pragma unroll
        for (int r = 0; r < 4; r++)
            tile[q * 4 + r][nt * 16 + m] = acc[nt][r];

    unsigned short* crow = C + (size_t)(wrow0 + m) * DD;
#pragma unroll
    for (int j = 0; j < 8; j++) {
        int col = q * 4 + 16 * j;
        float4 v = *(float4*)&tile[m][col];
        unsigned int lo = f2bf(v.x) | ((unsigned int)f2bf(v.y) << 16);
        unsigned int hi = f2bf(v.z) | ((unsigned int)f2bf(v.w) << 16);
        uint2 p; p.x = lo; p.y = hi;
        *(uint2*)(crow + col) = p;  // 8 B aligned
    }
}

// ---- CSR gather-aggregate: ONE NODE PER WAVE (max TLP — 60000 waves; R8/R9
// showed multi-node waves + fused-stat atomics regress 2-4x). Unroll 8 to cover
// the avg-11 edge row in ~1.5 dependent load batches. No stats fusion: per-block
// atomics into the 16-line sums array serialize in TCC (R9: +150 us/dispatch).
__global__ __launch_bounds__(256) void gather_kernel(const unsigned short* __restrict__ xw,
                                                     const int* __restrict__ rowptr,
                                                     const int2* __restrict__ csr,
                                                     unsigned short* __restrict__ agg) {
    int wid = (int)((blockIdx.x * 256 + threadIdx.x) >> 6);
    int l = threadIdx.x & 63;
    if (wid >= NN) return;
    int beg = rowptr[wid], end = rowptr[wid + 1];
    float ax = 0.f, ay = 0.f;
    int i = beg;
    for (; i + 8 <= end; i += 8) {
        unsigned int u[8];
        float c[8];
#pragma unroll
        for (int j = 0; j < 8; j++) {
            int2 r = csr[i + j];
            u[j] = *(const unsigned int*)(xw + (size_t)r.x * DD + 2 * l);
            c[j] = __int_as_float(r.y);
        }
#pragma unroll
        for (int j = 0; j < 8; j++) {
            ax += bflo(u[j]) * c[j];
            ay += bfhi(u[j]) * c[j];
        }
    }
    for (; i + 2 <= end; i += 2) {
        int2 r0 = csr[i], r1 = csr[i + 1];
        unsigned int u0 = *(const unsigned int*)(xw + (size_t)r0.x * DD + 2 * l);
        unsigned int u1 = *(const unsigned int*)(xw + (size_t)r1.x * DD + 2 * l);
        float c0 = __int_as_float(r0.y), c1 = __int_as_float(r1.y);
        ax += bflo(u0) * c0 + bflo(u1) * c1;
        ay += bfhi(u0) * c0 + bfhi(u1) * c1;
    }
    if (i < end) {
        int2 r0 = csr[i];
        unsigned int u0 = *(const unsigned int*)(xw + (size_t)r0.x * DD + 2 * l);
        float c0 = __int_as_float(r0.y);
        ax += bflo(u0) * c0;
        ay += bfhi(u0) * c0;
    }
    ((unsigned int*)(agg + (size_t)wid * DD))[l] = (unsigned int)f2bf(ax) | ((unsigned int)f2bf(ay) << 16);
}

// ---- batchnorm stats on bf16 agg: sums[0..127]=sum, sums[128..255]=sumsq ----
__global__ __launch_bounds__(256) void bnstat_kernel(const unsigned short* __restrict__ h, float* __restrict__ sums) {
    int d2 = threadIdx.x & 63;   // feature pair
    int rg = threadIdx.x >> 6;   // 0..3
    int r0 = blockIdx.x * 256 + rg;
    float s0 = 0.f, q0 = 0.f, s1 = 0.f, q1 = 0.f;
    for (int i = 0; i < 64; i++) {
        int r = r0 + 4 * i;
        if (r < NN) {
            unsigned int u = *(const unsigned int*)(h + (size_t)r * DD + 2 * d2);
            float v0 = bflo(u), v1 = bfhi(u);
            s0 += v0; q0 += v0 * v0;
            s1 += v1; q1 += v1 * v1;
        }
    }
    __shared__ float lds[4][4][64];  // [wave][component][lane] — conflict-free
    lds[rg][0][d2] = s0; lds[rg][1][d2] = q0;
    lds[rg][2][d2] = s1; lds[rg][3][d2] = q1;
    __syncthreads();
    int l2 = threadIdx.x & 63, jj = threadIdx.x >> 6;
    float v = lds[0][jj][l2] + lds[1][jj][l2] + lds[2][jj][l2] + lds[3][jj][l2];
    int addr = (jj & 1) * 128 + 2 * l2 + (jj >> 1);
    atomicAdd(&sums[addr], v);
}

// ---- fold sums -> scale/shift: scale=g*rsqrt(var+eps), shift=be-mu*scale ----
__global__ __launch_bounds__(128) void bnfin_kernel(const float* __restrict__ sums,
                                                    const float* __restrict__ g,
                                                    const float* __restrict__ be,
                                                    float* __restrict__ normp) {
    int d = threadIdx.x;
    const float invN = 1.0f / (float)NN;
    float mu = sums[d] * invN;
    float var = sums[128 + d] * invN - mu * mu;
    float sc = rsqrtf(var + 1e-5f) * g[d];
    normp[d] = sc;
    normp[128 + d] = be[d] - mu * sc;
}

// ---- final: out_fp32 = bf16(agg)*scale+shift (normp precomputed by bnfin) ----
__global__ __launch_bounds__(256) void bnapply_kernel(const unsigned short* __restrict__ h,
                                                      const float* __restrict__ normp,
                                                      float* __restrict__ out) {
    int idx = blockIdx.x * 256 + threadIdx.x;  // one per 4 elements
    if (idx >= NN * DD / 4) return;
    int d = (idx * 4) & 127;
    uint2 u = *(const uint2*)(h + idx * 4);
    float4 sc = *(const float4*)&normp[d];
    float4 sh = *(const float4*)&normp[128 + d];
    float4 o;
    o.x = fmaf(bflo(u.x), sc.x, sh.x);
    o.y = fmaf(bfhi(u.x), sc.y, sh.y);
    o.z = fmaf(bflo(u.y), sc.z, sh.z);
    o.w = fmaf(bfhi(u.y), sc.w, sh.w);
    *(float4*)&out[idx * 4] = o;
}

extern "C" void kernel_launch(void* const* d_in, const int* in_sizes, int n_in,
                              void* d_out, int out_size, void* d_ws, size_t ws_size,
                              hipStream_t stream) {
    const float* x = (const float*)d_in[0];
    const int* ei = (const int*)d_in[1];
    const int* srcp = ei;
    const int* dstp = ei + NE;
    const float* w[3]  = {(const float*)d_in[2], (const float*)d_in[6],  (const float*)d_in[10]};
    const float* g[3]  = {(const float*)d_in[4], (const float*)d_in[8],  (const float*)d_in[12]};
    const float* be[3] = {(const float*)d_in[5], (const float*)d_in[9],  (const float*)d_in[13]};

    // workspace layout (~43 MB), all chunks 16-B aligned
    unsigned short* xwb  = (unsigned short*)d_ws;        // bf16 xw  [NN*DD]
    unsigned short* aggb = xwb + (size_t)NN * DD;        // bf16 agg [NN*DD]
    int* deg    = (int*)(aggb + (size_t)NN * DD);        // [NN]
    int* cursor = deg + NN;                              // [NN]
    int* rowptr = cursor + NN;                           // [NN+16]
    float* dinv = (float*)(rowptr + NN + 16);            // [NN]
    float* sums = dinv + NN;                             // [3*256]
    float* ss   = sums + 3 * 256;                        // [3*256] scale/shift per layer
    int* partials = (int*)(ss + 3 * 256);                // [256]
    int* blockoff = partials + 256;                      // [256]
    unsigned short* Wt = (unsigned short*)(blockoff + 256);  // [3*128*128] bf16
    int2* csr = (int2*)(Wt + 3 * DD * DD);               // [NTOT] packed {src, coef}
    float* out = (float*)d_out;

    // ---- CSR build (once; edge_index constant across layers) ----
    hipMemsetAsync(deg, 0, 2 * NN * sizeof(int), stream);        // deg + cursor
    hipMemsetAsync(sums, 0, 3 * 256 * sizeof(float), stream);    // all layers' stats
    deg_kernel<<<(NE + 255) / 256, 256, 0, stream>>>(dstp, deg);
    scanA_kernel<<<NB, 256, 0, stream>>>(deg, partials, dinv);
    scanB_kernel<<<1, 256, 0, stream>>>(partials, blockoff, rowptr);
    scanC_kernel<<<NB, 256, 0, stream>>>(deg, blockoff, rowptr);
    fill_kernel<<<(NTOT + 255) / 256, 256, 0, stream>>>(srcp, dstp, rowptr, cursor, dinv, csr);
    wcvt_kernel<<<(3 * 64 * DD + 255) / 256, 256, 0, stream>>>(w[0], w[1], w[2], Wt);

    const int GEMM_GRID = (NN / 16 + 3) / 4;    // 938
    const int GATHER_GRID = (NN + 3) / 4;       // 15000 (one node per wave)
    for (int L = 0; L < 3; ++L) {
        const float* normp = (L == 0) ? nullptr : (ss + (L - 1) * 256);
        if (L == 0)
            gemm_mfma_kernel<false><<<GEMM_GRID, 256, 0, stream>>>(x, Wt, normp, xwb);
        else
            gemm_mfma_kernel<true><<<GEMM_GRID, 256, 0, stream>>>(aggb, Wt + L * DD * DD, normp, xwb);
        gather_kernel<<<GATHER_GRID, 256, 0, stream>>>(xwb, rowptr, csr, aggb);
        bnstat_kernel<<<(NN + 255) / 256, 256, 0, stream>>>(aggb, sums + L * 256);
        bnfin_kernel<<<1, 128, 0, stream>>>(sums + L * 256, g[L], be[L], ss + L * 256);
        if (L == 2)
            bnapply_kernel<<<(NN * DD / 4 + 255) / 256, 256, 0, stream>>>(aggb, ss + L * 256, out);
    }
}

// Round 11
// 396.842 us; speedup vs baseline: 2.1471x; 1.0846x over previous
//
#include <hip/hip_runtime.h>
#include <hip/hip_bf16.h>

#define NN 60000
#define NE 600000
#define DD 128
#define NTOT (NE + NN)
#define NB ((NN + 255) / 256)   // 235 blocks for scan

typedef __attribute__((ext_vector_type(8))) short short8;
typedef __attribute__((ext_vector_type(4))) float f32x4;

__device__ __forceinline__ unsigned short f2bf(float f) {
    unsigned int u = __float_as_uint(f);
    unsigned int r = (u + 0x7FFF + ((u >> 16) & 1)) >> 16;  // RNE
    return (unsigned short)r;
}
__device__ __forceinline__ float bflo(unsigned int u) { return __uint_as_float(u << 16); }
__device__ __forceinline__ float bfhi(unsigned int u) { return __uint_as_float(u & 0xFFFF0000u); }

// ---- degree (edges only; +1 self-loop folded in later) ----
__global__ __launch_bounds__(256) void deg_kernel(const int* __restrict__ dst, int* __restrict__ deg) {
    int e = blockIdx.x * 256 + threadIdx.x;
    if (e < NE) atomicAdd(&deg[dst[e]], 1);
}

// ---- scanA: per-block sums of (deg+1), fused dinv ----
__global__ __launch_bounds__(256) void scanA_kernel(const int* __restrict__ deg, int* __restrict__ partials,
                                                    float* __restrict__ dinv) {
    __shared__ int lds[256];
    int i = blockIdx.x * 256 + threadIdx.x;
    int dv = (i < NN) ? deg[i] : 0;
    if (i < NN) dinv[i] = rsqrtf((float)(dv + 1));
    int v = (i < NN) ? dv + 1 : 0;
    lds[threadIdx.x] = v;
    __syncthreads();
    for (int off = 128; off > 0; off >>= 1) {
        if (threadIdx.x < off) lds[threadIdx.x] += lds[threadIdx.x + off];
        __syncthreads();
    }
    if (threadIdx.x == 0) partials[blockIdx.x] = lds[0];
}

__global__ __launch_bounds__(256) void scanB_kernel(const int* __restrict__ partials,
                                                    int* __restrict__ blockoff,
                                                    int* __restrict__ rowptr) {
    __shared__ int lds[256];
    int t = threadIdx.x;
    int v = (t < NB) ? partials[t] : 0;
    lds[t] = v;
    __syncthreads();
    for (int off = 1; off < 256; off <<= 1) {
        int u = (t >= off) ? lds[t - off] : 0;
        __syncthreads();
        lds[t] += u;
        __syncthreads();
    }
    if (t < NB) blockoff[t] = lds[t] - v;  // exclusive
    if (t == 0) rowptr[NN] = NTOT;
}

__global__ __launch_bounds__(256) void scanC_kernel(const int* __restrict__ deg,
                                                    const int* __restrict__ blockoff,
                                                    int* __restrict__ rowptr) {
    __shared__ int lds[256];
    int i = blockIdx.x * 256 + threadIdx.x;
    int t = threadIdx.x;
    int v = (i < NN) ? deg[i] + 1 : 0;
    lds[t] = v;
    __syncthreads();
    for (int off = 1; off < 256; off <<= 1) {
        int u = (t >= off) ? lds[t - off] : 0;
        __syncthreads();
        lds[t] += u;
        __syncthreads();
    }
    if (i < NN) rowptr[i] = blockoff[blockIdx.x] + lds[t] - v;
}

// ---- CSR fill: packed int2{src, coef_bits} -> ONE 8B scattered store per edge ----
__global__ __launch_bounds__(256) void fill_kernel(const int* __restrict__ src, const int* __restrict__ dst,
                                                   const int* __restrict__ rowptr, int* __restrict__ cursor,
                                                   const float* __restrict__ dinv,
                                                   int2* __restrict__ csr) {
    int e = blockIdx.x * 256 + threadIdx.x;
    if (e >= NTOT) return;
    int s, t;
    if (e < NE) { s = src[e]; t = dst[e]; }
    else { s = t = e - NE; }
    int pos = atomicAdd(&cursor[t], 1);
    int2 rec;
    rec.x = s;
    rec.y = __float_as_int(dinv[s] * dinv[t]);
    csr[rowptr[t] + pos] = rec;
}

// ---- W convert to MFMA-fragment-major order, all 3 layers ----
// Wsw[L][kc][nt][lane] = 8 bf16: B-frag element (n = nt*16 + (lane&15),
// k = kc*32 + (lane>>4)*8 + j). One wave's B-frag load is then lane-consecutive
// 16B = one fully-coalesced 1KB instruction (was 16-way row-split before).
__global__ __launch_bounds__(256) void wcvt_kernel(const float* __restrict__ W0, const float* __restrict__ W1,
                                                   const float* __restrict__ W2, unsigned short* __restrict__ Wsw) {
    int idx = blockIdx.x * 256 + threadIdx.x;  // 3 * 32 frags * 64 lanes = 6144
    if (idx >= 3 * 32 * 64) return;
    int L = idx >> 11;           // /2048
    int rem = idx & 2047;
    int frag = rem >> 6;         // 0..31  (kc*8 + nt)
    int lane = rem & 63;
    int kc = frag >> 3, nt = frag & 7;
    int m = lane & 15, q = lane >> 4;
    int n = nt * 16 + m;
    int k0 = kc * 32 + q * 8;
    const float* W = (L == 0) ? W0 : (L == 1) ? W1 : W2;
    unsigned int p[4];
#pragma unroll
    for (int j = 0; j < 4; j++) {
        unsigned int b0 = f2bf(W[(size_t)(k0 + 2 * j) * DD + n]);
        unsigned int b1 = f2bf(W[(size_t)(k0 + 2 * j + 1) * DD + n]);
        p[j] = b0 | (b1 << 16);
    }
    uint4 o; o.x = p[0]; o.y = p[1]; o.z = p[2]; o.w = p[3];
    *(uint4*)(Wsw + ((size_t)L * 2048 + (size_t)frag * 64 + lane) * 8) = o;
}

// ---- MFMA GEMM: C_bf16[NN x 128] = f(A) @ W ----
// R11 redesign: all VMEM coalesced. A staged via LDS (coalesced uint4 global
// loads + fused normp/leaky/cvt, XOR-swizzled chunks -> bank-balanced
// ds_read_b128 frags); B from fragment-major Wsw (1KB coalesced loads);
// epilogue full-line stores. LDS 16KB A + 17.4KB repack = 33.8KB (4 blk/CU).
// NOTE: no waves/EU hint — (256,4) caused 64-VGPR cap + acc spill (R3).
template <bool BF16IN>
__global__ __launch_bounds__(256) void gemm_mfma_kernel(const void* __restrict__ Ain,
                                                        const unsigned short* __restrict__ Wsw,
                                                        const float* __restrict__ normp,
                                                        unsigned short* __restrict__ C) {
    __shared__ unsigned short Atile[64 * 128];  // 16 KB, swizzled 16B chunks
    __shared__ float rep[4][16][68];            // 17.4 KB, per-wave repack
    int tid = threadIdx.x;
    int wslot = tid >> 6;
    int l = tid & 63;
    int m = l & 15;
    int q = l >> 4;
    int rblk = blockIdx.x * 64;

    // ---- staging: 4 passes, all 256 threads (no early exit: barrier) ----
#pragma unroll
    for (int p = 0; p < 4; p++) {
        int rowl = p * 16 + (tid >> 4);   // block-local row 0..63
        int c = tid & 15;                  // 16B chunk (8 shorts / 8 ks)
        int row = min(rblk + rowl, NN - 1);
        float a[8];
        if (BF16IN) {
            uint4 u = *(const uint4*)((const unsigned short*)Ain + (size_t)row * DD + c * 8);
            a[0] = bflo(u.x); a[1] = bfhi(u.x); a[2] = bflo(u.y); a[3] = bfhi(u.y);
            a[4] = bflo(u.z); a[5] = bfhi(u.z); a[6] = bflo(u.w); a[7] = bfhi(u.w);
        } else {
            const float* Af = (const float*)Ain + (size_t)row * DD + c * 8;
            float4 x0 = *(const float4*)Af;
            float4 x1 = *(const float4*)(Af + 4);
            a[0] = x0.x; a[1] = x0.y; a[2] = x0.z; a[3] = x0.w;
            a[4] = x1.x; a[5] = x1.y; a[6] = x1.z; a[7] = x1.w;
        }
        if (normp) {
#pragma unroll
            for (int j = 0; j < 8; j++) {
                float v = fmaf(a[j], normp[c * 8 + j], normp[128 + c * 8 + j]);
                a[j] = (v >= 0.f) ? v : 0.01f * v;
            }
        }
        unsigned int w0 = f2bf(a[0]) | ((unsigned int)f2bf(a[1]) << 16);
        unsigned int w1 = f2bf(a[2]) | ((unsigned int)f2bf(a[3]) << 16);
        unsigned int w2 = f2bf(a[4]) | ((unsigned int)f2bf(a[5]) << 16);
        unsigned int w3 = f2bf(a[6]) | ((unsigned int)f2bf(a[7]) << 16);
        uint4 wv; wv.x = w0; wv.y = w1; wv.z = w2; wv.w = w3;
        *(uint4*)&Atile[rowl * 128 + ((c ^ (rowl & 15)) * 8)] = wv;
    }
    __syncthreads();

    // ---- MFMA main: 4 k-chunks x 8 col-tiles ----
    f32x4 acc[8];
#pragma unroll
    for (int i = 0; i < 8; i++) acc[i] = (f32x4){0.f, 0.f, 0.f, 0.f};
    int rowl_w = wslot * 16 + m;
#pragma unroll
    for (int kc = 0; kc < 4; kc++) {
        short8 af = *(const short8*)&Atile[rowl_w * 128 + (((kc * 4 + q) ^ m) * 8)];
#pragma unroll
        for (int nt = 0; nt < 8; nt++) {
            short8 bf = *(const short8*)(Wsw + ((size_t)(kc * 8 + nt) * 64 + l) * 8);
            acc[nt] = __builtin_amdgcn_mfma_f32_16x16x32_bf16(af, bf, acc[nt], 0, 0, 0);
        }
    }

    // ---- epilogue: 2-pass per-wave repack, full-line 32B/lane stores ----
    int wrow0 = rblk + wslot * 16;
    int r2 = l >> 2, c2 = l & 3;
#pragma unroll
    for (int pass = 0; pass < 2; pass++) {
#pragma unroll
        for (int ntl = 0; ntl < 4; ntl++) {
            f32x4 a = acc[pass * 4 + ntl];
#pragma unroll
            for (int r = 0; r < 4; r++)
                rep[wslot][q * 4 + r][ntl * 16 + m] = a[r];
        }
        // wave-internal RAW: compiler inserts lgkmcnt (same pattern as R6-R10)
        const float* tr = &rep[wslot][r2][c2 * 16];
        float4 v0 = *(const float4*)(tr);
        float4 v1 = *(const float4*)(tr + 4);
        float4 v2 = *(const float4*)(tr + 8);
        float4 v3 = *(const float4*)(tr + 12);
        uint4 oA, oB;
        oA.x = f2bf(v0.x) | ((unsigned int)f2bf(v0.y) << 16);
        oA.y = f2bf(v0.z) | ((unsigned int)f2bf(v0.w) << 16);
        oA.z = f2bf(v1.x) | ((unsigned int)f2bf(v1.y) << 16);
        oA.w = f2bf(v1.z) | ((unsigned int)f2bf(v1.w) << 16);
        oB.x = f2bf(v2.x) | ((unsigned int)f2bf(v2.y) << 16);
        oB.y = f2bf(v2.z) | ((unsigned int)f2bf(v2.w) << 16);
        oB.z = f2bf(v3.x) | ((unsigned int)f2bf(v3.y) << 16);
        oB.w = f2bf(v3.z) | ((unsigned int)f2bf(v3.w) << 16);
        int row = wrow0 + r2;
        if (row < NN) {
            unsigned short* cp = C + (size_t)row * DD + pass * 64 + c2 * 16;
            *(uint4*)cp = oA;
            *(uint4*)(cp + 8) = oB;
        }
    }
}

// ---- CSR gather-aggregate: ONE NODE PER WAVE (max TLP — 60000 waves; R8/R9
// showed multi-node waves + fused-stat atomics regress 2-4x). Unroll 8. ----
__global__ __launch_bounds__(256) void gather_kernel(const unsigned short* __restrict__ xw,
                                                     const int* __restrict__ rowptr,
                                                     const int2* __restrict__ csr,
                                                     unsigned short* __restrict__ agg) {
    int wid = (int)((blockIdx.x * 256 + threadIdx.x) >> 6);
    int l = threadIdx.x & 63;
    if (wid >= NN) return;
    int beg = rowptr[wid], end = rowptr[wid + 1];
    float ax = 0.f, ay = 0.f;
    int i = beg;
    for (; i + 8 <= end; i += 8) {
        unsigned int u[8];
        float c[8];
#pragma unroll
        for (int j = 0; j < 8; j++) {
            int2 r = csr[i + j];
            u[j] = *(const unsigned int*)(xw + (size_t)r.x * DD + 2 * l);
            c[j] = __int_as_float(r.y);
        }
#pragma unroll
        for (int j = 0; j < 8; j++) {
            ax += bflo(u[j]) * c[j];
            ay += bfhi(u[j]) * c[j];
        }
    }
    for (; i + 2 <= end; i += 2) {
        int2 r0 = csr[i], r1 = csr[i + 1];
        unsigned int u0 = *(const unsigned int*)(xw + (size_t)r0.x * DD + 2 * l);
        unsigned int u1 = *(const unsigned int*)(xw + (size_t)r1.x * DD + 2 * l);
        float c0 = __int_as_float(r0.y), c1 = __int_as_float(r1.y);
        ax += bflo(u0) * c0 + bflo(u1) * c1;
        ay += bfhi(u0) * c0 + bfhi(u1) * c1;
    }
    if (i < end) {
        int2 r0 = csr[i];
        unsigned int u0 = *(const unsigned int*)(xw + (size_t)r0.x * DD + 2 * l);
        float c0 = __int_as_float(r0.y);
        ax += bflo(u0) * c0;
        ay += bfhi(u0) * c0;
    }
    ((unsigned int*)(agg + (size_t)wid * DD))[l] = (unsigned int)f2bf(ax) | ((unsigned int)f2bf(ay) << 16);
}

// ---- batchnorm stats on bf16 agg: sums[0..127]=sum, sums[128..255]=sumsq ----
__global__ __launch_bounds__(256) void bnstat_kernel(const unsigned short* __restrict__ h, float* __restrict__ sums) {
    int d2 = threadIdx.x & 63;   // feature pair
    int rg = threadIdx.x >> 6;   // 0..3
    int r0 = blockIdx.x * 256 + rg;
    float s0 = 0.f, q0 = 0.f, s1 = 0.f, q1 = 0.f;
    for (int i = 0; i < 64; i++) {
        int r = r0 + 4 * i;
        if (r < NN) {
            unsigned int u = *(const unsigned int*)(h + (size_t)r * DD + 2 * d2);
            float v0 = bflo(u), v1 = bfhi(u);
            s0 += v0; q0 += v0 * v0;
            s1 += v1; q1 += v1 * v1;
        }
    }
    __shared__ float lds[4][4][64];  // [wave][component][lane] — conflict-free
    lds[rg][0][d2] = s0; lds[rg][1][d2] = q0;
    lds[rg][2][d2] = s1; lds[rg][3][d2] = q1;
    __syncthreads();
    int l2 = threadIdx.x & 63, jj = threadIdx.x >> 6;
    float v = lds[0][jj][l2] + lds[1][jj][l2] + lds[2][jj][l2] + lds[3][jj][l2];
    int addr = (jj & 1) * 128 + 2 * l2 + (jj >> 1);
    atomicAdd(&sums[addr], v);
}

// ---- fold sums -> scale/shift: scale=g*rsqrt(var+eps), shift=be-mu*scale ----
__global__ __launch_bounds__(128) void bnfin_kernel(const float* __restrict__ sums,
                                                    const float* __restrict__ g,
                                                    const float* __restrict__ be,
                                                    float* __restrict__ normp) {
    int d = threadIdx.x;
    const float invN = 1.0f / (float)NN;
    float mu = sums[d] * invN;
    float var = sums[128 + d] * invN - mu * mu;
    float sc = rsqrtf(var + 1e-5f) * g[d];
    normp[d] = sc;
    normp[128 + d] = be[d] - mu * sc;
}

// ---- final: out_fp32 = bf16(agg)*scale+shift (normp precomputed by bnfin) ----
__global__ __launch_bounds__(256) void bnapply_kernel(const unsigned short* __restrict__ h,
                                                      const float* __restrict__ normp,
                                                      float* __restrict__ out) {
    int idx = blockIdx.x * 256 + threadIdx.x;  // one per 4 elements
    if (idx >= NN * DD / 4) return;
    int d = (idx * 4) & 127;
    uint2 u = *(const uint2*)(h + idx * 4);
    float4 sc = *(const float4*)&normp[d];
    float4 sh = *(const float4*)&normp[128 + d];
    float4 o;
    o.x = fmaf(bflo(u.x), sc.x, sh.x);
    o.y = fmaf(bfhi(u.x), sc.y, sh.y);
    o.z = fmaf(bflo(u.y), sc.z, sh.z);
    o.w = fmaf(bfhi(u.y), sc.w, sh.w);
    *(float4*)&out[idx * 4] = o;
}

extern "C" void kernel_launch(void* const* d_in, const int* in_sizes, int n_in,
                              void* d_out, int out_size, void* d_ws, size_t ws_size,
                              hipStream_t stream) {
    const float* x = (const float*)d_in[0];
    const int* ei = (const int*)d_in[1];
    const int* srcp = ei;
    const int* dstp = ei + NE;
    const float* w[3]  = {(const float*)d_in[2], (const float*)d_in[6],  (const float*)d_in[10]};
    const float* g[3]  = {(const float*)d_in[4], (const float*)d_in[8],  (const float*)d_in[12]};
    const float* be[3] = {(const float*)d_in[5], (const float*)d_in[9],  (const float*)d_in[13]};

    // workspace layout (~43 MB), all chunks 16-B aligned
    unsigned short* xwb  = (unsigned short*)d_ws;        // bf16 xw  [NN*DD]
    unsigned short* aggb = xwb + (size_t)NN * DD;        // bf16 agg [NN*DD]
    int* deg    = (int*)(aggb + (size_t)NN * DD);        // [NN]
    int* cursor = deg + NN;                              // [NN]
    int* rowptr = cursor + NN;                           // [NN+16]
    float* dinv = (float*)(rowptr + NN + 16);            // [NN]
    float* sums = dinv + NN;                             // [3*256]
    float* ss   = sums + 3 * 256;                        // [3*256] scale/shift per layer
    int* partials = (int*)(ss + 3 * 256);                // [256]
    int* blockoff = partials + 256;                      // [256]
    unsigned short* Wsw = (unsigned short*)(blockoff + 256);  // [3*128*128] bf16 frag-major
    int2* csr = (int2*)(Wsw + 3 * DD * DD);              // [NTOT] packed {src, coef}
    float* out = (float*)d_out;

    // ---- CSR build (once; edge_index constant across layers) ----
    hipMemsetAsync(deg, 0, 2 * NN * sizeof(int), stream);        // deg + cursor
    hipMemsetAsync(sums, 0, 3 * 256 * sizeof(float), stream);    // all layers' stats
    deg_kernel<<<(NE + 255) / 256, 256, 0, stream>>>(dstp, deg);
    scanA_kernel<<<NB, 256, 0, stream>>>(deg, partials, dinv);
    scanB_kernel<<<1, 256, 0, stream>>>(partials, blockoff, rowptr);
    scanC_kernel<<<NB, 256, 0, stream>>>(deg, blockoff, rowptr);
    fill_kernel<<<(NTOT + 255) / 256, 256, 0, stream>>>(srcp, dstp, rowptr, cursor, dinv, csr);
    wcvt_kernel<<<24, 256, 0, stream>>>(w[0], w[1], w[2], Wsw);

    const int GEMM_GRID = (NN + 63) / 64;       // 938
    const int GATHER_GRID = (NN + 3) / 4;       // 15000 (one node per wave)
    for (int L = 0; L < 3; ++L) {
        const float* normp = (L == 0) ? nullptr : (ss + (L - 1) * 256);
        if (L == 0)
            gemm_mfma_kernel<false><<<GEMM_GRID, 256, 0, stream>>>(x, Wsw, normp, xwb);
        else
            gemm_mfma_kernel<true><<<GEMM_GRID, 256, 0, stream>>>(aggb, Wsw + (size_t)L * DD * DD, normp, xwb);
        gather_kernel<<<GATHER_GRID, 256, 0, stream>>>(xwb, rowptr, csr, aggb);
        bnstat_kernel<<<(NN + 255) / 256, 256, 0, stream>>>(aggb, sums + L * 256);
        bnfin_kernel<<<1, 128, 0, stream>>>(sums + L * 256, g[L], be[L], ss + L * 256);
        if (L == 2)
            bnapply_kernel<<<(NN * DD / 4 + 255) / 256, 256, 0, stream>>>(aggb, ss + L * 256, out);
    }
}